// Round 7
// baseline (226.812 us; speedup 1.0000x reference)
//
#include <hip/hip_runtime.h>
#include <math.h>

// B=64, N=27, D=512. EPS=1e-5.
// Identities: (1) both cross-attns have K/V constant along the key axis ->
// uniform softmax -> output == the V row; all N^2 tensors are broadcasts of
// (B,D) vectors. (2) msg BN stats decompose: per-i/per-j sums + 27x27 Gram.
// (3) eE = eN@E1^T = rs*(e0@E1^T - m*rowsum(E1)) -- fused into the E1 GEMM.
// R6 post-mortem: fp32 512^3 weight-collapse GEMMs were the 43.8us gate
// (latency-bound, <=1 blk/CU). Dropped; activation chain runs directly via
// densek_job (~6us/step). 9 dispatches, all proven job code.

#define EPSC 1e-5f

typedef short short8 __attribute__((ext_vector_type(8)));
typedef float f32x4 __attribute__((ext_vector_type(4)));

// ---- ws layout (float offsets) ----
#define YB_OFF   0u          // 1728*2048
#define GF_OFF   3538944u
#define G_OFF    3571712u
#define FVG_OFF  3604480u
#define HH_OFF   3637248u
#define E0_OFF   3670016u
#define EN_OFF   3702784u
#define EE_OFF   3735552u
#define XN_OFF   3768320u    // 884736
#define RE1_OFF  4653056u    // 512
#define PAC_OFF  4653568u    // 729 (atomic)
#define ST_OFF   4654336u    // 220 floats
// ST: [0..27) Sa, [27..54) Sa2, [54..81) Sc, [81..108) Sc2,
//     [108..135) sae(at), [135..162) sce(at), [162..164) se,se2(at),
//     [164..166) s_acc(at), [166..220) pbn_acc(at)

__device__ __forceinline__ unsigned short f2bf(float f) {
    unsigned int u = __float_as_uint(f);
    return (unsigned short)((u + 0x7FFFu + ((u >> 16) & 1u)) >> 16);
}

__device__ __forceinline__ float wred64(float v) {
#pragma unroll
    for (int o = 32; o; o >>= 1) v += __shfl_down(v, o, 64);
    return v;
}

// ============ job: bf16 MFMA GEMM Yb (proven R2) ============
__device__ void mfma_job(const float* __restrict__ X,
        const float* __restrict__ W0, const float* __restrict__ W1,
        const float* __restrict__ W2, const float* __restrict__ W3,
        float* __restrict__ Y, int bx, int by, int t, char* sbuf) {
    unsigned short* As = (unsigned short*)sbuf;
    unsigned short* Bs = As + 128 * 32;
    int rb0 = bx * 128;
    int n0 = by * 128;
    const float* Wsel;
    switch (by >> 2) {
        case 0: Wsel = W0; break; case 1: Wsel = W1; break;
        case 2: Wsel = W2; break; default: Wsel = W3; break;
    }
    int wrow0 = (by & 3) * 128;
    int tt = t & 127;
    int sr = (tt & 64) + (((tt & 1) << 5) | ((tt & 63) >> 1));
    bool isB = t >= 128;
    const float* src;
    bool valid;
    if (!isB) { int gr = rb0 + sr; valid = gr < 1728; src = X + (size_t)gr * 512; }
    else      { valid = true;      src = Wsel + (size_t)(wrow0 + sr) * 512; }
    unsigned short* dst = (isB ? Bs : As) + sr * 32;
    int rsh = (sr >> 1) & 3;
    int wave = t >> 6, l = t & 63;
    int wr = (wave >> 1) * 64, wc = (wave & 1) * 64;
    int lr = l & 15, g = l >> 4;
    f32x4 acc[4][4] = {};
    float4 v[8];
    float4 z4 = make_float4(0.f, 0.f, 0.f, 0.f);
#pragma unroll
    for (int i = 0; i < 8; i++) v[i] = valid ? ((const float4*)src)[i] : z4;
    for (int step = 0; step < 16; step++) {
        __syncthreads();
#pragma unroll
        for (int s = 0; s < 4; s++) {
            uint4 pk;
            pk.x = f2bf(v[2 * s].x) | ((unsigned)f2bf(v[2 * s].y) << 16);
            pk.y = f2bf(v[2 * s].z) | ((unsigned)f2bf(v[2 * s].w) << 16);
            pk.z = f2bf(v[2 * s + 1].x) | ((unsigned)f2bf(v[2 * s + 1].y) << 16);
            pk.w = f2bf(v[2 * s + 1].z) | ((unsigned)f2bf(v[2 * s + 1].w) << 16);
            *(uint4*)(dst + (((s + rsh) & 3) << 3)) = pk;
        }
        if (step < 15) {
            const float4* nsrc = (const float4*)(src + (step + 1) * 32);
#pragma unroll
            for (int i = 0; i < 8; i++) v[i] = valid ? nsrc[i] : z4;
        }
        __syncthreads();
        short8 af[4], bf[4];
#pragma unroll
        for (int m = 0; m < 4; m++) {
            int r = wr + m * 16 + lr;
            af[m] = *(const short8*)(As + r * 32 + (((g + (r >> 1)) & 3) << 3));
        }
#pragma unroll
        for (int n = 0; n < 4; n++) {
            int r = wc + n * 16 + lr;
            bf[n] = *(const short8*)(Bs + r * 32 + (((g + (r >> 1)) & 3) << 3));
        }
#pragma unroll
        for (int m = 0; m < 4; m++)
#pragma unroll
            for (int n = 0; n < 4; n++)
                acc[m][n] = __builtin_amdgcn_mfma_f32_16x16x32_bf16(af[m], bf[n], acc[m][n], 0, 0, 0);
    }
#pragma unroll
    for (int m = 0; m < 4; m++) {
        int row0 = rb0 + wr + m * 16 + g * 4;
#pragma unroll
        for (int reg = 0; reg < 4; reg++) {
            int row = row0 + reg;
            if (row < 1728) {
#pragma unroll
                for (int n = 0; n < 4; n++)
                    Y[(size_t)row * 2048 + n0 + wc + n * 16 + lr] = acc[m][n][reg];
            }
        }
    }
}

// ============ job: coalesced matvec / rowsum, 64 outputs per block ============
__device__ void mv_cw(const float* __restrict__ W, const float* __restrict__ vin,
                      const float* __restrict__ badd, float* __restrict__ vout,
                      int jb, int t, char* sbuf) {
    float* vs = (float*)sbuf;
    if (t < 128) {
        float4 one = make_float4(1.f, 1.f, 1.f, 1.f);
        ((float4*)vs)[t] = vin ? ((const float4*)vin)[t] : one;
    }
    __syncthreads();
    int w = t >> 6, lane = t & 63;
    for (int o = 0; o < 16; o++) {
        int d = jb * 64 + w * 16 + o;
        const float* row = W + (size_t)d * 512;
        float4 v1 = *(const float4*)(row + lane * 4);
        float4 v2 = *(const float4*)(row + 256 + lane * 4);
        const float* va = vs + lane * 4;
        const float* vb = vs + 256 + lane * 4;
        float p = v1.x * va[0] + v1.y * va[1] + v1.z * va[2] + v1.w * va[3]
                + v2.x * vb[0] + v2.y * vb[1] + v2.z * vb[2] + v2.w * vb[3];
        p = wred64(p);
        if (lane == 0) vout[d] = p + (badd ? badd[d] : 0.f);
    }
}

// ============ job: Out[64x512] = A[64x512] @ W[512x512]^T (16 d's/block) ============
// mode 0: +bias store. 1: per-d batch-BN + relu. 2: +bias store + global stats
// atomics -> ST[164,165]. 3: eE epilogue: e = rs*(acc - m*rE1[d]), store,
// se/se2 atomics -> ST[162,163].
__device__ void densek_job(const float* __restrict__ A, const float* __restrict__ W,
                           const float* __restrict__ bias, float* __restrict__ Out,
                           int jb, int t, char* sbuf, int mode,
                           float* __restrict__ ST, const float* __restrict__ rE1) {
    float* As = (float*)sbuf;          // [128][66] transposed: As[k][b]
    float* Ws = As + 128 * 66;         // [16][132]
    float* red = Ws + 16 * 132;        // [8]
    int d0 = jb * 16;
    int b = t & 63, dg = t >> 6;
    float m = 0.f, rs = 0.f;
    if (mode == 3) {
        m = ST[164] * (1.f / 32768.f);
        float var = ST[165] * (1.f / 32768.f) - m * m;
        rs = 1.f / sqrtf(var + EPSC);
    }
    float acc[4] = {0.f, 0.f, 0.f, 0.f};
    for (int c = 0; c < 4; c++) {
        int k0 = c * 128;
#pragma unroll
        for (int r = 0; r < 8; r++) {
            int p = t + r * 256;
            int row = p >> 5, c4 = p & 31;
            float4 vv = *(const float4*)(A + (size_t)row * 512 + k0 + c4 * 4);
            As[(c4 * 4 + 0) * 66 + row] = vv.x;
            As[(c4 * 4 + 1) * 66 + row] = vv.y;
            As[(c4 * 4 + 2) * 66 + row] = vv.z;
            As[(c4 * 4 + 3) * 66 + row] = vv.w;
        }
#pragma unroll
        for (int r = 0; r < 2; r++) {
            int p = t + r * 256;
            int drow = p >> 5, c4 = p & 31;
            *(float4*)(Ws + drow * 132 + c4 * 4) =
                *(const float4*)(W + (size_t)(d0 + drow) * 512 + k0 + c4 * 4);
        }
        __syncthreads();
#pragma unroll 4
        for (int k = 0; k < 128; k += 4) {
            float x0 = As[(k + 0) * 66 + b], x1 = As[(k + 1) * 66 + b];
            float x2 = As[(k + 2) * 66 + b], x3 = As[(k + 3) * 66 + b];
#pragma unroll
            for (int i = 0; i < 4; i++) {
                float4 wv = *(const float4*)(Ws + (dg + i * 4) * 132 + k);
                acc[i] = fmaf(x0, wv.x, fmaf(x1, wv.y, fmaf(x2, wv.z, fmaf(x3, wv.w, acc[i]))));
            }
        }
        __syncthreads();
    }
    float s = 0.f, s2 = 0.f;
#pragma unroll
    for (int i = 0; i < 4; i++) {
        int d = d0 + dg + i * 4;
        float val = acc[i] + (bias ? bias[d] : 0.f);
        if (mode == 1) {
            float sv = __shfl(wred64(val), 0, 64);
            float sv2 = __shfl(wred64(val * val), 0, 64);
            float mm = sv * (1.f / 64.f);
            float var = sv2 * (1.f / 64.f) - mm * mm;
            val = fmaxf((val - mm) / sqrtf(var + EPSC), 0.f);
        } else if (mode == 3) {
            val = rs * (val - m * rE1[d]);
        }
        Out[b * 512 + d] = val;
        s += val; s2 = fmaf(val, val, s2);
    }
    if (mode == 2 || mode == 3) {
        s = wred64(s); s2 = wred64(s2);
        if ((t & 63) == 0) { red[dg * 2] = s; red[dg * 2 + 1] = s2; }
        __syncthreads();
        if (t == 0) {
            float* dstp = ST + (mode == 2 ? 164 : 162);
            atomicAdd(dstp,     red[0] + red[2] + red[4] + red[6]);
            atomicAdd(dstp + 1, red[1] + red[3] + red[5] + red[7]);
        }
    }
}

// ============ job: Gram partials (atomic) ============
__device__ void gram_job(const float* __restrict__ Yb, float* __restrict__ pac,
                         int b, int t, char* sbuf) {
    float* As = (float*)sbuf;        // [27][132]
    float* Cs = As + 27 * 132;
    float a0 = 0, a1 = 0, a2 = 0;
    int i = t / 9, j0 = (t % 9) * 3;
    for (int dc = 0; dc < 4; dc++) {
        const float* base = Yb + (size_t)b * 27 * 2048 + dc * 128;
        for (int id = t; id < 864; id += 256) {
            int row = id >> 5, c4 = (id & 31) << 2;
            *(float4*)&As[row * 132 + c4] = *(const float4*)(base + (size_t)row * 2048 + c4);
            *(float4*)&Cs[row * 132 + c4] = *(const float4*)(base + (size_t)row * 2048 + 512 + c4);
        }
        __syncthreads();
        if (t < 243) {
#pragma unroll
            for (int k = 0; k < 128; k += 4) {
                float4 av = *(const float4*)&As[i * 132 + k];
                float4 c0 = *(const float4*)&Cs[j0 * 132 + k];
                float4 c1 = *(const float4*)&Cs[(j0 + 1) * 132 + k];
                float4 c2 = *(const float4*)&Cs[(j0 + 2) * 132 + k];
                a0 += av.x * c0.x + av.y * c0.y + av.z * c0.z + av.w * c0.w;
                a1 += av.x * c1.x + av.y * c1.y + av.z * c1.z + av.w * c1.w;
                a2 += av.x * c2.x + av.y * c2.y + av.z * c2.z + av.w * c2.w;
            }
        }
        __syncthreads();
    }
    if (t < 243) {
        atomicAdd(pac + i * 27 + j0, a0);
        atomicAdd(pac + i * 27 + j0 + 1, a1);
        atomicAdd(pac + i * 27 + j0 + 2, a2);
    }
}

// ============ job: per-i a/c sums ============
__device__ void acsum_job(const float* __restrict__ Yb, float* __restrict__ ST,
                          int ia, int t, char* sbuf) {
    int i = ia < 27 ? ia : ia - 27;
    int off = ia < 27 ? 0 : 512;
    float s = 0, s2 = 0;
    for (int q = t; q < 32768; q += 256) {
        int b = q >> 9, d = q & 511;
        float v = Yb[(size_t)(b * 27 + i) * 2048 + off + d];
        s += v; s2 = fmaf(v, v, s2);
    }
    s = wred64(s); s2 = wred64(s2);
    float* p = (float*)sbuf;
    int wv_ = t >> 6;
    if ((t & 63) == 0) { p[wv_ * 2] = s; p[wv_ * 2 + 1] = s2; }
    __syncthreads();
    if (t == 0) {
        float S = p[0] + p[2] + p[4] + p[6];
        float S2 = p[1] + p[3] + p[5] + p[7];
        if (ia < 27) { ST[ia] = S; ST[27 + ia] = S2; }
        else { ST[54 + (ia - 27)] = S; ST[81 + (ia - 27)] = S2; }
    }
}

// ============ D0: Yb MFMA + gf + rE1 + zero ============
__global__ __launch_bounds__(256) void d0_k(const float* __restrict__ x,
        const float* __restrict__ A1, const float* __restrict__ B1,
        const float* __restrict__ V1, const float* __restrict__ U1,
        const float* __restrict__ E1, float* __restrict__ ws) {
    __shared__ __align__(16) char sbuf[16384];
    int blk = blockIdx.x, t = threadIdx.x;
    if (blk < 224) {
        mfma_job(x, A1, B1, V1, U1, ws + YB_OFF, blk % 14, blk / 14, t, sbuf);
    } else if (blk < 240) {
        int jb = blk - 224;
        float* gf = ws + GF_OFF;
        for (int p = 0; p < 8; p++) {
            int q = jb * 2048 + p * 256 + t;
            int b = q >> 9, d = q & 511;
            const float* pp = x + (size_t)b * 13824 + d;
            float s = 0.f;
#pragma unroll
            for (int n = 0; n < 27; n++) s += pp[n << 9];
            gf[q] = s * (1.0f / 27.0f);
        }
    } else if (blk < 248) {
        mv_cw(E1, nullptr, nullptr, ws + RE1_OFF, blk - 240, t, sbuf);
    } else {
        float* pac = ws + PAC_OFF;
        float* ST = ws + ST_OFF;
        for (int q = t; q < 729; q += 256) pac[q] = 0.f;
        if (t < 112) ST[108 + t] = 0.f;
    }
}

// ============ D1: g = relu(BN(gf@gl^T+b)) + gram ============
__global__ __launch_bounds__(256) void d1_k(const float* __restrict__ gl_w,
        const float* __restrict__ gl_b, float* __restrict__ ws) {
    __shared__ __align__(16) char sbuf[42400];
    int blk = blockIdx.x, t = threadIdx.x;
    if (blk < 32) {
        densek_job(ws + GF_OFF, gl_w, gl_b, ws + G_OFF, blk, t, sbuf, 1, nullptr, nullptr);
    } else {
        gram_job(ws + YB_OFF, ws + PAC_OFF, blk - 32, t, sbuf);
    }
}

// ============ D2: fvg = g@fv^T+b + acsum ============
__global__ __launch_bounds__(256) void d2_k(const float* __restrict__ fv_w,
        const float* __restrict__ fv_b, float* __restrict__ ws) {
    __shared__ __align__(16) char sbuf[42400];
    int blk = blockIdx.x, t = threadIdx.x;
    if (blk < 32) {
        densek_job(ws + G_OFF, fv_w, fv_b, ws + FVG_OFF, blk, t, sbuf, 0, nullptr, nullptr);
    } else {
        acsum_job(ws + YB_OFF, ws + ST_OFF, blk - 32, t, sbuf);
    }
}

// ============ D3: h = fvg@av^T+b ============
__global__ __launch_bounds__(256) void d3_k(const float* __restrict__ av_w,
        const float* __restrict__ av_b, float* __restrict__ ws) {
    __shared__ __align__(16) char sbuf[42400];
    densek_job(ws + FVG_OFF, av_w, av_b, ws + HH_OFF, blockIdx.x, threadIdx.x,
               sbuf, 0, nullptr, nullptr);
}

// ============ D4: e0 = h@ep^T+b with global stats ============
__global__ __launch_bounds__(256) void d4_k(const float* __restrict__ ep_w,
        const float* __restrict__ ep_b, float* __restrict__ ws) {
    __shared__ __align__(16) char sbuf[42400];
    densek_job(ws + HH_OFF, ep_w, ep_b, ws + E0_OFF, blockIdx.x, threadIdx.x,
               sbuf, 2, ws + ST_OFF, nullptr);
}

// ============ D5: eE = rs*(e0@E1^T - m*rE1) + se atomics; eN elementwise ============
__global__ __launch_bounds__(256) void d5_k(const float* __restrict__ E1,
        float* __restrict__ ws) {
    __shared__ __align__(16) char sbuf[42400];
    int blk = blockIdx.x, t = threadIdx.x;
    float* ST = ws + ST_OFF;
    if (blk < 32) {
        densek_job(ws + E0_OFF, E1, nullptr, ws + EE_OFF, blk, t, sbuf, 3,
                   ST, ws + RE1_OFF);
    } else {
        float m = ST[164] * (1.f / 32768.f);
        float var = ST[165] * (1.f / 32768.f) - m * m;
        float rs = 1.f / sqrtf(var + EPSC);
        const float* e0 = ws + E0_OFF;
        float* eN = ws + EN_OFF;
        int base = (blk - 32) * 4096;
#pragma unroll
        for (int r = 0; r < 16; r++) {
            int q = base + r * 256 + t;
            eN[q] = (e0[q] - m) * rs;
        }
    }
}

// ============ D6: sae/sce partials ============
__global__ __launch_bounds__(256) void d6_k(float* __restrict__ ws) {
    __shared__ __align__(16) char sbuf[64];
    int blk = blockIdx.x, t = threadIdx.x;
    const float* Yb = ws + YB_OFF;
    const float* eE = ws + EE_OFF;
    float* ST = ws + ST_OFF;
    int i = blk % 27, bg = blk / 27;
    float sae = 0.f, sce = 0.f;
    for (int idx = t; idx < 4096; idx += 256) {
        int bb = bg * 8 + (idx >> 9), d = idx & 511;
        float e = eE[bb * 512 + d];
        size_t base = (size_t)(bb * 27 + i) * 2048 + d;
        sae = fmaf(Yb[base], e, sae);
        sce = fmaf(Yb[base + 512], e, sce);
    }
    sae = wred64(sae); sce = wred64(sce);
    float* p = (float*)sbuf;
    int wv_ = t >> 6;
    if ((t & 63) == 0) { p[wv_ * 2] = sae; p[wv_ * 2 + 1] = sce; }
    __syncthreads();
    if (t == 0) {
        atomicAdd(ST + 108 + i, p[0] + p[2] + p[4] + p[6]);
        atomicAdd(ST + 135 + i, p[1] + p[3] + p[5] + p[7]);
    }
}

// ============ D7: fuse gate/softmax/aggregate (proven) ============
__global__ __launch_bounds__(256) void d7_k(float* __restrict__ ws) {
    __shared__ __align__(16) char sbuf[5888];
    int blk = blockIdx.x, t = threadIdx.x;
    const float* Yb = ws + YB_OFF;
    const float* eE = ws + EE_OFF;
    const float* eN = ws + EN_OFF;
    const float* pac = ws + PAC_OFF;
    float* ST = ws + ST_OFF;
    float* xn = ws + XN_OFF;
    float* pbn_acc = ST + 166;
    float* rstL = (float*)sbuf;      // 736
    float* pmsL = rstL + 736;
    float Se = ST[162], Se2 = ST[163];
    const float inv = 1.f / 32768.f;
    for (int id = t; id < 729; id += 256) {
        int i = id / 27, j = id - i * 27;
        float m = (ST[i] + ST[54 + j] + Se) * inv;
        float S2 = ST[27 + i] + ST[81 + j] + Se2 + 2.f * (pac[id] + ST[108 + i] + ST[135 + j]);
        float var = S2 * inv - m * m;
        float rst = 1.f / sqrtf(var + EPSC);
        rstL[id] = rst; pmsL[id] = -m * rst;
    }
    __syncthreads();
    int b = blk >> 2, ds4 = (blk & 3) * 128;
    int j = t & 127, ih = t >> 7;
    float ev = eE[b * 512 + ds4 + j], env = eN[b * 512 + ds4 + j];
    float cr[27], ur[27];
#pragma unroll
    for (int jj = 0; jj < 27; ++jj) {
        size_t rb = (size_t)(b * 27 + jj) * 2048 + ds4 + j;
        cr[jj] = Yb[rb + 512];
        ur[jj] = Yb[rb + 1024];
    }
    const float L2E = 1.4426950408889634f;
    int i0 = ih ? 14 : 0, i1 = ih ? 27 : 14;
    for (int i = i0; i < i1; ++i) {
        size_t rb = (size_t)(b * 27 + i) * 2048 + ds4 + j;
        float t1 = Yb[rb] + ev;
        const float* prst = rstL + i * 27;
        const float* ppms = pmsL + i * 27;
        float num = 0.f, den = 0.f;
#pragma unroll
        for (int jj = 0; jj < 27; ++jj) {
            float bn = fmaf(t1 + cr[jj], prst[jj], ppms[jj]);
            float r = fmaxf(bn, 0.f);
            float z = env + r;
            float tt = __builtin_amdgcn_exp2f(z * -L2E);
            float sg = __builtin_amdgcn_rcpf(1.f + tt);
            float w2 = __builtin_amdgcn_exp2f(sg * L2E);
            den += w2;
            num = fmaf(w2, ur[jj], num);
        }
        xn[(size_t)b * 13824 + i * 512 + ds4 + j] =
            Yb[rb + 1536] + num * __builtin_amdgcn_rcpf(den) * (1.f / 27.f);
    }
    __syncthreads();
    if (t < 27) {
        float s = 0, s2 = 0;
        const float4* xp = (const float4*)(xn + (size_t)b * 13824 + t * 512 + ds4);
        for (int q = 0; q < 32; q++) {
            float4 v = xp[q];
            s += (v.x + v.y) + (v.z + v.w);
            s2 += v.x * v.x + v.y * v.y + v.z * v.z + v.w * v.w;
        }
        atomicAdd(pbn_acc + t * 2, s);
        atomicAdd(pbn_acc + t * 2 + 1, s2);
    }
}

// ============ D8: per-n BN + residual relu ============
__global__ __launch_bounds__(256) void d8_k(const float* __restrict__ x,
        float* __restrict__ ws, float* __restrict__ out) {
    __shared__ __align__(16) char sbuf[256];
    int blk = blockIdx.x, t = threadIdx.x;
    const float* xn = ws + XN_OFF;
    const float* pbn_acc = ws + ST_OFF + 166;
    float* m2L = (float*)sbuf;
    float* rs2L = m2L + 32;
    if (t < 27) {
        float S = pbn_acc[t * 2], S2 = pbn_acc[t * 2 + 1];
        float m = S * (1.f / 32768.f);
        float var = S2 * (1.f / 32768.f) - m * m;
        m2L[t] = m; rs2L[t] = 1.f / sqrtf(var + EPSC);
    }
    __syncthreads();
    int b = blk >> 2, ds4 = (blk & 3) * 128;
    int j = t & 127, nh = t >> 7;
    int n0 = nh * 14, n1 = nh ? 27 : 14;
    for (int n = n0; n < n1; ++n) {
        size_t xi = (size_t)b * 13824 + n * 512 + ds4 + j;
        out[xi] = fmaxf(fmaf(xn[xi] - m2L[n], rs2L[n], x[xi]), 0.f);
    }
}

extern "C" void kernel_launch(void* const* d_in, const int* in_sizes, int n_in,
                              void* d_out, int out_size, void* d_ws, size_t ws_size,
                              hipStream_t stream) {
    const float* x    = (const float*)d_in[0];
    const float* gl_w = (const float*)d_in[1];
    const float* gl_b = (const float*)d_in[2];
    const float* fv_w = (const float*)d_in[7];
    const float* fv_b = (const float*)d_in[8];
    const float* av_w = (const float*)d_in[13];
    const float* av_b = (const float*)d_in[14];
    const float* ep_w = (const float*)d_in[15];
    const float* ep_b = (const float*)d_in[16];
    const float* U1   = (const float*)d_in[17];
    const float* V1   = (const float*)d_in[18];
    const float* A1   = (const float*)d_in[19];
    const float* B1   = (const float*)d_in[20];
    const float* E1   = (const float*)d_in[21];
    float* out = (float*)d_out;
    float* ws = (float*)d_ws;

    d0_k<<<249, 256, 0, stream>>>(x, A1, B1, V1, U1, E1, ws);
    d1_k<<<96, 256, 0, stream>>>(gl_w, gl_b, ws);
    d2_k<<<86, 256, 0, stream>>>(fv_w, fv_b, ws);
    d3_k<<<32, 256, 0, stream>>>(av_w, av_b, ws);
    d4_k<<<32, 256, 0, stream>>>(ep_w, ep_b, ws);
    d5_k<<<40, 256, 0, stream>>>(E1, ws);
    d6_k<<<216, 256, 0, stream>>>(ws);
    d7_k<<<256, 256, 0, stream>>>(ws);
    d8_k<<<256, 256, 0, stream>>>(x, ws, out);
}

// Round 8
// 165.691 us; speedup vs baseline: 1.3689x; 1.3689x over previous
//
#include <hip/hip_runtime.h>
#include <math.h>

// B=64, N=27, D=512. EPS=1e-5.
// Identities: (1) both cross-attns have K/V constant along the key axis ->
// uniform softmax -> output == the V row; all N^2 tensors are broadcasts of
// (B,D) vectors. (2) msg BN stats decompose: per-i/per-j sums + 27x27 Gram.
// (3) eE = eN@E1^T = rs*(e0@E1^T - m*rowsum(E1)) -- fused into the E1 GEMM.
// R7 post-mortem: merging extra jobs into the MFMA kernel doubled it (80us,
// latency-stall; compiler scheduling pessimized). d0 is DEDICATED again.
// Chain GEMMs re-gridded to 128 blocks x 4 outputs.

#define EPSC 1e-5f

typedef short short8 __attribute__((ext_vector_type(8)));
typedef float f32x4 __attribute__((ext_vector_type(4)));

// ---- ws layout (float offsets) ----
#define YB_OFF   0u          // 1728*2048
#define GF_OFF   3538944u
#define G_OFF    3571712u
#define FVG_OFF  3604480u
#define HH_OFF   3637248u
#define E0_OFF   3670016u
#define EN_OFF   3702784u
#define EE_OFF   3735552u
#define XN_OFF   3768320u    // 884736
#define RE1_OFF  4653056u    // 512
#define PAC_OFF  4653568u    // 729 (atomic)
#define ST_OFF   4654336u    // 220 floats
// ST: [0..27) Sa, [27..54) Sa2, [54..81) Sc, [81..108) Sc2,
//     [108..135) sae(at), [135..162) sce(at), [162..164) se,se2(at),
//     [164..166) s_acc(at), [166..220) pbn_acc(at)

__device__ __forceinline__ unsigned short f2bf(float f) {
    unsigned int u = __float_as_uint(f);
    return (unsigned short)((u + 0x7FFFu + ((u >> 16) & 1u)) >> 16);
}

__device__ __forceinline__ float wred64(float v) {
#pragma unroll
    for (int o = 32; o; o >>= 1) v += __shfl_down(v, o, 64);
    return v;
}

// ============ D0: bf16 MFMA GEMM Yb — DEDICATED kernel (R6 verbatim) ============
__global__ __launch_bounds__(256) void d0_k(const float* __restrict__ X,
        const float* __restrict__ W0, const float* __restrict__ W1,
        const float* __restrict__ W2, const float* __restrict__ W3,
        float* __restrict__ Y) {
    __shared__ __align__(16) unsigned short As[128 * 32];
    __shared__ __align__(16) unsigned short Bs[128 * 32];
    int t = threadIdx.x;
    int bx = blockIdx.x % 14, by = blockIdx.x / 14;
    int rb0 = bx * 128;
    int n0 = by * 128;
    const float* Wsel;
    switch (by >> 2) {
        case 0: Wsel = W0; break; case 1: Wsel = W1; break;
        case 2: Wsel = W2; break; default: Wsel = W3; break;
    }
    int wrow0 = (by & 3) * 128;
    int tt = t & 127;
    int sr = (tt & 64) + (((tt & 1) << 5) | ((tt & 63) >> 1));
    bool isB = t >= 128;
    const float* src;
    bool valid;
    if (!isB) { int gr = rb0 + sr; valid = gr < 1728; src = X + (size_t)gr * 512; }
    else      { valid = true;      src = Wsel + (size_t)(wrow0 + sr) * 512; }
    unsigned short* dst = (isB ? Bs : As) + sr * 32;
    int rsh = (sr >> 1) & 3;
    int wave = t >> 6, l = t & 63;
    int wr = (wave >> 1) * 64, wc = (wave & 1) * 64;
    int lr = l & 15, g = l >> 4;
    f32x4 acc[4][4] = {};
    float4 v[8];
    float4 z4 = make_float4(0.f, 0.f, 0.f, 0.f);
#pragma unroll
    for (int i = 0; i < 8; i++) v[i] = valid ? ((const float4*)src)[i] : z4;
    for (int step = 0; step < 16; step++) {
        __syncthreads();
#pragma unroll
        for (int s = 0; s < 4; s++) {
            uint4 pk;
            pk.x = f2bf(v[2 * s].x) | ((unsigned)f2bf(v[2 * s].y) << 16);
            pk.y = f2bf(v[2 * s].z) | ((unsigned)f2bf(v[2 * s].w) << 16);
            pk.z = f2bf(v[2 * s + 1].x) | ((unsigned)f2bf(v[2 * s + 1].y) << 16);
            pk.w = f2bf(v[2 * s + 1].z) | ((unsigned)f2bf(v[2 * s + 1].w) << 16);
            *(uint4*)(dst + (((s + rsh) & 3) << 3)) = pk;
        }
        if (step < 15) {   // prefetch BEFORE the compute barrier: in flight
            const float4* nsrc = (const float4*)(src + (step + 1) * 32);
#pragma unroll
            for (int i = 0; i < 8; i++) v[i] = valid ? nsrc[i] : z4;
        }
        __syncthreads();
        short8 af[4], bf[4];
#pragma unroll
        for (int m = 0; m < 4; m++) {
            int r = wr + m * 16 + lr;
            af[m] = *(const short8*)(As + r * 32 + (((g + (r >> 1)) & 3) << 3));
        }
#pragma unroll
        for (int n = 0; n < 4; n++) {
            int r = wc + n * 16 + lr;
            bf[n] = *(const short8*)(Bs + r * 32 + (((g + (r >> 1)) & 3) << 3));
        }
#pragma unroll
        for (int m = 0; m < 4; m++)
#pragma unroll
            for (int n = 0; n < 4; n++)
                acc[m][n] = __builtin_amdgcn_mfma_f32_16x16x32_bf16(af[m], bf[n], acc[m][n], 0, 0, 0);
    }
#pragma unroll
    for (int m = 0; m < 4; m++) {
        int row0 = rb0 + wr + m * 16 + g * 4;
#pragma unroll
        for (int reg = 0; reg < 4; reg++) {
            int row = row0 + reg;
            if (row < 1728) {
#pragma unroll
                for (int n = 0; n < 4; n++)
                    Y[(size_t)row * 2048 + n0 + wc + n * 16 + lr] = acc[m][n][reg];
            }
        }
    }
}

// ============ job: coalesced matvec / rowsum, 64 outputs per block ============
__device__ void mv_cw(const float* __restrict__ W, const float* __restrict__ vin,
                      const float* __restrict__ badd, float* __restrict__ vout,
                      int jb, int t, char* sbuf) {
    float* vs = (float*)sbuf;
    if (t < 128) {
        float4 one = make_float4(1.f, 1.f, 1.f, 1.f);
        ((float4*)vs)[t] = vin ? ((const float4*)vin)[t] : one;
    }
    __syncthreads();
    int w = t >> 6, lane = t & 63;
    for (int o = 0; o < 16; o++) {
        int d = jb * 64 + w * 16 + o;
        const float* row = W + (size_t)d * 512;
        float4 v1 = *(const float4*)(row + lane * 4);
        float4 v2 = *(const float4*)(row + 256 + lane * 4);
        const float* va = vs + lane * 4;
        const float* vb = vs + 256 + lane * 4;
        float p = v1.x * va[0] + v1.y * va[1] + v1.z * va[2] + v1.w * va[3]
                + v2.x * vb[0] + v2.y * vb[1] + v2.z * vb[2] + v2.w * vb[3];
        p = wred64(p);
        if (lane == 0) vout[d] = p + (badd ? badd[d] : 0.f);
    }
}

// ============ d_pre: gf (16) + rE1 (8) + zero (1) ============
__global__ __launch_bounds__(256) void dpre_k(const float* __restrict__ x,
        const float* __restrict__ E1, float* __restrict__ ws) {
    __shared__ __align__(16) char sbuf[4096];
    int blk = blockIdx.x, t = threadIdx.x;
    if (blk < 16) {
        float* gf = ws + GF_OFF;
        for (int p = 0; p < 8; p++) {
            int q = blk * 2048 + p * 256 + t;
            int b = q >> 9, d = q & 511;
            const float* pp = x + (size_t)b * 13824 + d;
            float s = 0.f;
#pragma unroll
            for (int n = 0; n < 27; n++) s += pp[n << 9];
            gf[q] = s * (1.0f / 27.0f);
        }
    } else if (blk < 24) {
        mv_cw(E1, nullptr, nullptr, ws + RE1_OFF, blk - 16, t, sbuf);
    } else {
        float* pac = ws + PAC_OFF;
        float* ST = ws + ST_OFF;
        for (int q = t; q < 729; q += 256) pac[q] = 0.f;
        if (t < 112) ST[108 + t] = 0.f;
    }
}

// ============ job: Out[64x512] = A[64x512]@W^T, 4 d's/block (128 blocks) ============
// mode 0: +bias. 1: batch-BN+relu (wave==d). 2: +bias + stats->ST[164,165].
// 3: eE epilogue rs*(acc - m*rE1[d]) + se/se2->ST[162,163].
__device__ void dense4x_job(const float* __restrict__ A, const float* __restrict__ W,
                            const float* __restrict__ bias, float* __restrict__ Out,
                            int jb, int t, char* sbuf, int mode,
                            float* __restrict__ ST, const float* __restrict__ rE1) {
    float* As = (float*)sbuf;          // [128][65]
    float* Ws = As + 128 * 65;         // [4][132]
    float* red = Ws + 4 * 132;         // [8]
    int d0 = jb * 4;
    int b = t & 63, dg = t >> 6;       // wave index == dg
    int d = d0 + dg;
    float m = 0.f, rs = 0.f;
    if (mode == 3) {
        m = ST[164] * (1.f / 32768.f);
        float var = ST[165] * (1.f / 32768.f) - m * m;
        rs = 1.f / sqrtf(var + EPSC);
    }
    float acc = 0.f;
    for (int c = 0; c < 4; c++) {
        int k0 = c * 128;
#pragma unroll
        for (int r = 0; r < 8; r++) {
            int p = t + r * 256;
            int row = p >> 5, c4 = p & 31;
            float4 vv = *(const float4*)(A + (size_t)row * 512 + k0 + c4 * 4);
            As[(c4 * 4 + 0) * 65 + row] = vv.x;
            As[(c4 * 4 + 1) * 65 + row] = vv.y;
            As[(c4 * 4 + 2) * 65 + row] = vv.z;
            As[(c4 * 4 + 3) * 65 + row] = vv.w;
        }
        if (t < 128) {
            int drow = t >> 5, c4 = t & 31;
            *(float4*)(Ws + drow * 132 + c4 * 4) =
                *(const float4*)(W + (size_t)(d0 + drow) * 512 + k0 + c4 * 4);
        }
        __syncthreads();
#pragma unroll 8
        for (int k = 0; k < 128; k += 4) {
            float4 wv = *(const float4*)(Ws + dg * 132 + k);
            acc = fmaf(As[(k + 0) * 65 + b], wv.x, acc);
            acc = fmaf(As[(k + 1) * 65 + b], wv.y, acc);
            acc = fmaf(As[(k + 2) * 65 + b], wv.z, acc);
            acc = fmaf(As[(k + 3) * 65 + b], wv.w, acc);
        }
        __syncthreads();
    }
    float val = acc + (bias ? bias[d] : 0.f);
    if (mode == 1) {
        float sv = __shfl(wred64(val), 0, 64);
        float sv2 = __shfl(wred64(val * val), 0, 64);
        float mm = sv * (1.f / 64.f);
        float var = sv2 * (1.f / 64.f) - mm * mm;
        val = fmaxf((val - mm) / sqrtf(var + EPSC), 0.f);
    } else if (mode == 3) {
        val = rs * (val - m * rE1[d]);
    }
    Out[b * 512 + d] = val;
    if (mode == 2 || mode == 3) {
        float s = wred64(val), s2 = wred64(val * val);
        if ((t & 63) == 0) { red[dg * 2] = s; red[dg * 2 + 1] = s2; }
        __syncthreads();
        if (t == 0) {
            float* dstp = ST + (mode == 2 ? 164 : 162);
            atomicAdd(dstp,     red[0] + red[2] + red[4] + red[6]);
            atomicAdd(dstp + 1, red[1] + red[3] + red[5] + red[7]);
        }
    }
}

// ============ job: Gram partials (atomic) ============
__device__ void gram_job(const float* __restrict__ Yb, float* __restrict__ pac,
                         int b, int t, char* sbuf) {
    float* As = (float*)sbuf;        // [27][132]
    float* Cs = As + 27 * 132;
    float a0 = 0, a1 = 0, a2 = 0;
    int i = t / 9, j0 = (t % 9) * 3;
    for (int dc = 0; dc < 4; dc++) {
        const float* base = Yb + (size_t)b * 27 * 2048 + dc * 128;
        for (int id = t; id < 864; id += 256) {
            int row = id >> 5, c4 = (id & 31) << 2;
            *(float4*)&As[row * 132 + c4] = *(const float4*)(base + (size_t)row * 2048 + c4);
            *(float4*)&Cs[row * 132 + c4] = *(const float4*)(base + (size_t)row * 2048 + 512 + c4);
        }
        __syncthreads();
        if (t < 243) {
#pragma unroll
            for (int k = 0; k < 128; k += 4) {
                float4 av = *(const float4*)&As[i * 132 + k];
                float4 c0 = *(const float4*)&Cs[j0 * 132 + k];
                float4 c1 = *(const float4*)&Cs[(j0 + 1) * 132 + k];
                float4 c2 = *(const float4*)&Cs[(j0 + 2) * 132 + k];
                a0 += av.x * c0.x + av.y * c0.y + av.z * c0.z + av.w * c0.w;
                a1 += av.x * c1.x + av.y * c1.y + av.z * c1.z + av.w * c1.w;
                a2 += av.x * c2.x + av.y * c2.y + av.z * c2.z + av.w * c2.w;
            }
        }
        __syncthreads();
    }
    if (t < 243) {
        atomicAdd(pac + i * 27 + j0, a0);
        atomicAdd(pac + i * 27 + j0 + 1, a1);
        atomicAdd(pac + i * 27 + j0 + 2, a2);
    }
}

// ============ job: per-i a/c sums ============
__device__ void acsum_job(const float* __restrict__ Yb, float* __restrict__ ST,
                          int ia, int t, char* sbuf) {
    int i = ia < 27 ? ia : ia - 27;
    int off = ia < 27 ? 0 : 512;
    float s = 0, s2 = 0;
    for (int q = t; q < 32768; q += 256) {
        int b = q >> 9, d = q & 511;
        float v = Yb[(size_t)(b * 27 + i) * 2048 + off + d];
        s += v; s2 = fmaf(v, v, s2);
    }
    s = wred64(s); s2 = wred64(s2);
    float* p = (float*)sbuf;
    int wv_ = t >> 6;
    if ((t & 63) == 0) { p[wv_ * 2] = s; p[wv_ * 2 + 1] = s2; }
    __syncthreads();
    if (t == 0) {
        float S = p[0] + p[2] + p[4] + p[6];
        float S2 = p[1] + p[3] + p[5] + p[7];
        if (ia < 27) { ST[ia] = S; ST[27 + ia] = S2; }
        else { ST[54 + (ia - 27)] = S; ST[81 + (ia - 27)] = S2; }
    }
}

// ============ D2: g (128, mode1) + gram (64) + acsum (54) ============
__global__ __launch_bounds__(256) void d2_k(const float* __restrict__ gl_w,
        const float* __restrict__ gl_b, float* __restrict__ ws) {
    __shared__ __align__(16) char sbuf[36032];
    int blk = blockIdx.x, t = threadIdx.x;
    if (blk < 128) {
        dense4x_job(ws + GF_OFF, gl_w, gl_b, ws + G_OFF, blk, t, sbuf, 1, nullptr, nullptr);
    } else if (blk < 192) {
        gram_job(ws + YB_OFF, ws + PAC_OFF, blk - 128, t, sbuf);
    } else {
        acsum_job(ws + YB_OFF, ws + ST_OFF, blk - 192, t, sbuf);
    }
}

// ============ D3/D4/D5: chain GEMMs ============
__global__ __launch_bounds__(256) void d3_k(const float* __restrict__ fv_w,
        const float* __restrict__ fv_b, float* __restrict__ ws) {
    __shared__ __align__(16) char sbuf[36032];
    dense4x_job(ws + G_OFF, fv_w, fv_b, ws + FVG_OFF, blockIdx.x, threadIdx.x,
                sbuf, 0, nullptr, nullptr);
}

__global__ __launch_bounds__(256) void d4_k(const float* __restrict__ av_w,
        const float* __restrict__ av_b, float* __restrict__ ws) {
    __shared__ __align__(16) char sbuf[36032];
    dense4x_job(ws + FVG_OFF, av_w, av_b, ws + HH_OFF, blockIdx.x, threadIdx.x,
                sbuf, 0, nullptr, nullptr);
}

__global__ __launch_bounds__(256) void d5_k(const float* __restrict__ ep_w,
        const float* __restrict__ ep_b, float* __restrict__ ws) {
    __shared__ __align__(16) char sbuf[36032];
    dense4x_job(ws + HH_OFF, ep_w, ep_b, ws + E0_OFF, blockIdx.x, threadIdx.x,
                sbuf, 2, ws + ST_OFF, nullptr);
}

// ============ D6: eE (128, mode3) + eN elementwise (8) ============
__global__ __launch_bounds__(256) void d6_k(const float* __restrict__ E1,
        float* __restrict__ ws) {
    __shared__ __align__(16) char sbuf[36032];
    int blk = blockIdx.x, t = threadIdx.x;
    float* ST = ws + ST_OFF;
    if (blk < 128) {
        dense4x_job(ws + E0_OFF, E1, nullptr, ws + EE_OFF, blk, t, sbuf, 3,
                    ST, ws + RE1_OFF);
    } else {
        float m = ST[164] * (1.f / 32768.f);
        float var = ST[165] * (1.f / 32768.f) - m * m;
        float rs = 1.f / sqrtf(var + EPSC);
        const float* e0 = ws + E0_OFF;
        float* eN = ws + EN_OFF;
        int base = (blk - 128) * 4096;
#pragma unroll
        for (int r = 0; r < 16; r++) {
            int q = base + r * 256 + t;
            eN[q] = (e0[q] - m) * rs;
        }
    }
}

// ============ D7: sae/sce partials (216) ============
__global__ __launch_bounds__(256) void d7_k(float* __restrict__ ws) {
    __shared__ __align__(16) char sbuf[64];
    int blk = blockIdx.x, t = threadIdx.x;
    const float* Yb = ws + YB_OFF;
    const float* eE = ws + EE_OFF;
    float* ST = ws + ST_OFF;
    int i = blk % 27, bg = blk / 27;
    float sae = 0.f, sce = 0.f;
    for (int idx = t; idx < 4096; idx += 256) {
        int bb = bg * 8 + (idx >> 9), d = idx & 511;
        float e = eE[bb * 512 + d];
        size_t base = (size_t)(bb * 27 + i) * 2048 + d;
        sae = fmaf(Yb[base], e, sae);
        sce = fmaf(Yb[base + 512], e, sce);
    }
    sae = wred64(sae); sce = wred64(sce);
    float* p = (float*)sbuf;
    int wv_ = t >> 6;
    if ((t & 63) == 0) { p[wv_ * 2] = sae; p[wv_ * 2 + 1] = sce; }
    __syncthreads();
    if (t == 0) {
        atomicAdd(ST + 108 + i, p[0] + p[2] + p[4] + p[6]);
        atomicAdd(ST + 135 + i, p[1] + p[3] + p[5] + p[7]);
    }
}

// ============ D8: fuse gate/softmax/aggregate (proven) ============
__global__ __launch_bounds__(256) void d8_k(float* __restrict__ ws) {
    __shared__ __align__(16) char sbuf[5888];
    int blk = blockIdx.x, t = threadIdx.x;
    const float* Yb = ws + YB_OFF;
    const float* eE = ws + EE_OFF;
    const float* eN = ws + EN_OFF;
    const float* pac = ws + PAC_OFF;
    float* ST = ws + ST_OFF;
    float* xn = ws + XN_OFF;
    float* pbn_acc = ST + 166;
    float* rstL = (float*)sbuf;      // 736
    float* pmsL = rstL + 736;
    float Se = ST[162], Se2 = ST[163];
    const float inv = 1.f / 32768.f;
    for (int id = t; id < 729; id += 256) {
        int i = id / 27, j = id - i * 27;
        float m = (ST[i] + ST[54 + j] + Se) * inv;
        float S2 = ST[27 + i] + ST[81 + j] + Se2 + 2.f * (pac[id] + ST[108 + i] + ST[135 + j]);
        float var = S2 * inv - m * m;
        float rst = 1.f / sqrtf(var + EPSC);
        rstL[id] = rst; pmsL[id] = -m * rst;
    }
    __syncthreads();
    int b = blk >> 2, ds4 = (blk & 3) * 128;
    int j = t & 127, ih = t >> 7;
    float ev = eE[b * 512 + ds4 + j], env = eN[b * 512 + ds4 + j];
    float cr[27], ur[27];
#pragma unroll
    for (int jj = 0; jj < 27; ++jj) {
        size_t rb = (size_t)(b * 27 + jj) * 2048 + ds4 + j;
        cr[jj] = Yb[rb + 512];
        ur[jj] = Yb[rb + 1024];
    }
    const float L2E = 1.4426950408889634f;
    int i0 = ih ? 14 : 0, i1 = ih ? 27 : 14;
    for (int i = i0; i < i1; ++i) {
        size_t rb = (size_t)(b * 27 + i) * 2048 + ds4 + j;
        float t1 = Yb[rb] + ev;
        const float* prst = rstL + i * 27;
        const float* ppms = pmsL + i * 27;
        float num = 0.f, den = 0.f;
#pragma unroll
        for (int jj = 0; jj < 27; ++jj) {
            float bn = fmaf(t1 + cr[jj], prst[jj], ppms[jj]);
            float r = fmaxf(bn, 0.f);
            float z = env + r;
            float tt = __builtin_amdgcn_exp2f(z * -L2E);
            float sg = __builtin_amdgcn_rcpf(1.f + tt);
            float w2 = __builtin_amdgcn_exp2f(sg * L2E);
            den += w2;
            num = fmaf(w2, ur[jj], num);
        }
        xn[(size_t)b * 13824 + i * 512 + ds4 + j] =
            Yb[rb + 1536] + num * __builtin_amdgcn_rcpf(den) * (1.f / 27.f);
    }
    __syncthreads();
    if (t < 27) {
        float s = 0, s2 = 0;
        const float4* xp = (const float4*)(xn + (size_t)b * 13824 + t * 512 + ds4);
        for (int q = 0; q < 32; q++) {
            float4 v = xp[q];
            s += (v.x + v.y) + (v.z + v.w);
            s2 += v.x * v.x + v.y * v.y + v.z * v.z + v.w * v.w;
        }
        atomicAdd(pbn_acc + t * 2, s);
        atomicAdd(pbn_acc + t * 2 + 1, s2);
    }
}

// ============ D9: per-n BN + residual relu ============
__global__ __launch_bounds__(256) void d9_k(const float* __restrict__ x,
        float* __restrict__ ws, float* __restrict__ out) {
    __shared__ __align__(16) char sbuf[256];
    int blk = blockIdx.x, t = threadIdx.x;
    const float* xn = ws + XN_OFF;
    const float* pbn_acc = ws + ST_OFF + 166;
    float* m2L = (float*)sbuf;
    float* rs2L = m2L + 32;
    if (t < 27) {
        float S = pbn_acc[t * 2], S2 = pbn_acc[t * 2 + 1];
        float m = S * (1.f / 32768.f);
        float var = S2 * (1.f / 32768.f) - m * m;
        m2L[t] = m; rs2L[t] = 1.f / sqrtf(var + EPSC);
    }
    __syncthreads();
    int b = blk >> 2, ds4 = (blk & 3) * 128;
    int j = t & 127, nh = t >> 7;
    int n0 = nh * 14, n1 = nh ? 27 : 14;
    for (int n = n0; n < n1; ++n) {
        size_t xi = (size_t)b * 13824 + n * 512 + ds4 + j;
        out[xi] = fmaxf(fmaf(xn[xi] - m2L[n], rs2L[n], x[xi]), 0.f);
    }
}

extern "C" void kernel_launch(void* const* d_in, const int* in_sizes, int n_in,
                              void* d_out, int out_size, void* d_ws, size_t ws_size,
                              hipStream_t stream) {
    const float* x    = (const float*)d_in[0];
    const float* gl_w = (const float*)d_in[1];
    const float* gl_b = (const float*)d_in[2];
    const float* fv_w = (const float*)d_in[7];
    const float* fv_b = (const float*)d_in[8];
    const float* av_w = (const float*)d_in[13];
    const float* av_b = (const float*)d_in[14];
    const float* ep_w = (const float*)d_in[15];
    const float* ep_b = (const float*)d_in[16];
    const float* U1   = (const float*)d_in[17];
    const float* V1   = (const float*)d_in[18];
    const float* A1   = (const float*)d_in[19];
    const float* B1   = (const float*)d_in[20];
    const float* E1   = (const float*)d_in[21];
    float* out = (float*)d_out;
    float* ws = (float*)d_ws;

    dpre_k<<<25, 256, 0, stream>>>(x, E1, ws);
    d0_k<<<224, 256, 0, stream>>>(x, A1, B1, V1, U1, ws + YB_OFF);
    d2_k<<<246, 256, 0, stream>>>(gl_w, gl_b, ws);
    d3_k<<<128, 256, 0, stream>>>(fv_w, fv_b, ws);
    d4_k<<<128, 256, 0, stream>>>(av_w, av_b, ws);
    d5_k<<<128, 256, 0, stream>>>(ep_w, ep_b, ws);
    d6_k<<<136, 256, 0, stream>>>(E1, ws);
    d7_k<<<216, 256, 0, stream>>>(ws);
    d8_k<<<256, 256, 0, stream>>>(ws);
    d9_k<<<256, 256, 0, stream>>>(x, ws, out);
}